// Round 8
// baseline (529.505 us; speedup 1.0000x reference)
//
#include <hip/hip_runtime.h>

// Problem constants (from reference)
#define BATCH 1024
#define NL    64
#define NH    32
#define NG    20000
#define NC    64
#define GOI   1000

#define NGRP   313              // ceil(NG/64)
#define RGS    16               // row-groups of 64 batch rows
#define SLICES 64               // gene/ngroup slices
#define NBLK   (RGS * SLICES)   // 1024 blocks

typedef __attribute__((ext_vector_type(8))) short  short8;
typedef __attribute__((ext_vector_type(4))) float  f32x4;

static __device__ __forceinline__ unsigned short f2bf(float f) {
    unsigned int u = __builtin_bit_cast(unsigned int, f);
    // round-to-nearest-even
    unsigned int r = (u + 0x7fffu + ((u >> 16) & 1u)) >> 16;
    return (unsigned short)r;
}

// ---------------------------------------------------------------------------
// Single kernel, NO cross-block communication (R7 lesson: cross-XCD
// visibility of plain stores is not worth fighting for a 0.5 µs h).
// Each block: (rg, s) = 64 batch rows x a contiguous gene/ngroup slice.
//   1. stage W in LDS; compute h for its 64 rows into LDS (redundant per
//      block; identical accumulation order to the verified h_kernel).
//   2. __syncthreads (intra-block only).
//   3. logit: waves own 16 rows each; loop g over ~16 CONSECUTIVE genes ->
//      each output row receives sequential 256 B chunks (~4 KB contiguous
//      run) -- the write-page-locality experiment.
//   4. rho: same rows x ~5 consecutive 64-wide n-groups.
// MFMA scheme identical to R6 (passed): mfma(table_frag, h_frag),
// lane l15 = batch row, acc[r] = 4 consecutive output cols -> dwordx4.
// ---------------------------------------------------------------------------
__global__ __launch_bounds__(256) void fused_kernel(
    const float* __restrict__ latent,  // [BATCH][NL]
    const float* __restrict__ W,       // [NL][NH]
    const float* __restrict__ bias,    // [NH]
    const float* __restrict__ gamma,   // [NH]
    const float* __restrict__ beta,    // [NH]
    const float* __restrict__ mean,    // [NH]
    const float* __restrict__ var,     // [NH]
    const float* __restrict__ ltab,    // [NG][NH][NC]
    const int*   __restrict__ genes,   // [GOI]
    const float* __restrict__ rtab,    // [NG][NH]
    float*       __restrict__ out_logit, // [BATCH][GOI][NC]
    float*       __restrict__ out_rho)   // [BATCH][NG]
{
    __shared__ float          Wl[NL * NH];        // 8 KB
    __shared__ unsigned short hl[64 * NH];        // 4 KB (this block's h rows)

    const int tid = threadIdx.x;
    const int bid = blockIdx.x;
    const int rg  = bid & (RGS - 1);   // row-group
    const int s   = bid >> 4;          // slice
    const int r0  = rg * 64;           // first batch row

    // ---- stage W ----------------------------------------------------------
    {
        f32x4*       dst = (f32x4*)Wl;
        const f32x4* src = (const f32x4*)W;
        dst[tid * 2]     = src[tid * 2];
        dst[tid * 2 + 1] = src[tid * 2 + 1];
    }
    __syncthreads();

    // ---- h for our 64 rows (4 threads/row x 8 k each) ---------------------
    {
        const int lrow = tid >> 2;           // 0..63
        const int k0   = (tid & 3) * 8;      // 0,8,16,24
        const float* lp = latent + (long long)(r0 + lrow) * NL;
        float acc[8] = {0.f,0.f,0.f,0.f,0.f,0.f,0.f,0.f};
        #pragma unroll
        for (int jb = 0; jb < NL / 4; ++jb) {
            const f32x4 l4 = *(const f32x4*)(lp + jb * 4);
            #pragma unroll
            for (int i = 0; i < 4; ++i) {
                const int j = jb * 4 + i;
                #pragma unroll
                for (int jj = 0; jj < 8; ++jj)
                    acc[jj] += l4[i] * Wl[j * NH + k0 + jj];
            }
        }
        short8 pack;
        #pragma unroll
        for (int jj = 0; jj < 8; ++jj) {
            const int k = k0 + jj;
            float x = acc[jj] + bias[k];
            x = (x - mean[k]) * rsqrtf(var[k] + 1e-5f) * gamma[k] + beta[k];
            pack[jj] = (short)f2bf(fmaxf(x, 0.f));
        }
        *(short8*)&hl[lrow * NH + k0] = pack;
    }
    __syncthreads();

    // ---- MFMA phase -------------------------------------------------------
    const int wave = tid >> 6;
    const int lane = tid & 63;
    const int l15  = lane & 15;
    const int quad = lane >> 4;

    // B-operand (h frag): n = l15 = batch row within wave's 16, k = quad*8+j
    const short8 af = *(const short8*)&hl[(wave * 16 + l15) * NH + quad * 8];
    const long long brow = (long long)(r0 + wave * 16 + l15);

    // ---- logit: consecutive genes [g0, g1) --------------------------------
    const int g0 = (s * GOI) >> 6;
    const int g1 = ((s + 1) * GOI) >> 6;
    for (int g = g0; g < g1; ++g) {
        const long long gene = (long long)genes[g];
        const float* lw = ltab + gene * (long long)(NH * NC);
        // A-operand: m = c-within-tile = l15, k = quad*8 + j
        short8 bf[4];
        #pragma unroll
        for (int t = 0; t < 4; ++t) {
            #pragma unroll
            for (int j = 0; j < 8; ++j)
                bf[t][j] = (short)f2bf(lw[(quad * 8 + j) * NC + t * 16 + l15]);
        }
        float* op = out_logit + (brow * GOI + g) * NC + quad * 4;
        #pragma unroll
        for (int t = 0; t < 4; ++t) {
            f32x4 z = {0.f, 0.f, 0.f, 0.f};
            f32x4 acc = __builtin_amdgcn_mfma_f32_16x16x32_bf16(bf[t], af, z, 0, 0, 0);
            // D: col = l15 = batch row, row = quad*4+r = c (consecutive)
            *(f32x4*)(op + t * 16) = acc;
        }
    }

    // ---- rho: consecutive n-groups [n0g, n1g) -----------------------------
    const int n0g = (s * NGRP) >> 6;
    const int n1g = ((s + 1) * NGRP) >> 6;
    for (int ng = n0g; ng < n1g; ++ng) {
        #pragma unroll
        for (int t = 0; t < 4; ++t) {
            const int n0 = ng * 64 + t * 16;
            if (n0 < NG) {
                const float* rp = rtab + (long long)(n0 + l15) * NH + quad * 8;
                short8 bfr;
                #pragma unroll
                for (int j = 0; j < 8; ++j)
                    bfr[j] = (short)f2bf(rp[j]);
                f32x4 z = {0.f, 0.f, 0.f, 0.f};
                f32x4 acc = __builtin_amdgcn_mfma_f32_16x16x32_bf16(bfr, af, z, 0, 0, 0);
                *(f32x4*)(out_rho + brow * NG + n0 + quad * 4) = acc;
            }
        }
    }
}

extern "C" void kernel_launch(void* const* d_in, const int* in_sizes, int n_in,
                              void* d_out, int out_size, void* d_ws, size_t ws_size,
                              hipStream_t stream) {
    const float* latent = (const float*)d_in[0];
    const int*   genes  = (const int*)d_in[1];
    const float* W      = (const float*)d_in[2];
    const float* bias   = (const float*)d_in[3];
    const float* gamma  = (const float*)d_in[4];
    const float* beta   = (const float*)d_in[5];
    const float* mean   = (const float*)d_in[6];
    const float* var    = (const float*)d_in[7];
    const float* ltab   = (const float*)d_in[8];
    const float* rtab   = (const float*)d_in[9];

    float* out = (float*)d_out;
    float* out_logit = out;
    float* out_rho   = out + (long long)BATCH * GOI * NC;

    fused_kernel<<<dim3(NBLK), 256, 0, stream>>>(
        latent, W, bias, gamma, beta, mean, var,
        ltab, genes, rtab, out_logit, out_rho);
}